// Round 11
// baseline (731.348 us; speedup 1.0000x reference)
//
#include <hip/hip_runtime.h>
#include <hip/hip_bf16.h>

typedef unsigned short u16;
typedef unsigned int u32;
typedef float floatx4 __attribute__((ext_vector_type(4)));
typedef _Float16 f16x8 __attribute__((ext_vector_type(8)));

#define NN 8192
#define DD 512
#define NPARTS 4
#define JCHUNK 2048       // NN / NPARTS
#define RB_PER_PART 64    // 128-row blocks: 64*128 == 8192 exactly

__device__ __forceinline__ u16 f2h(float f) {
    _Float16 h = (_Float16)f;                 // RNE
    return __builtin_bit_cast(u16, h);
}
__device__ __forceinline__ float h2f(u16 u) {
    _Float16 h = __builtin_bit_cast(_Float16, u);
    return (float)h;
}

// async 16B-per-lane global->LDS DMA (wave-uniform LDS base + lane*16).
__device__ __forceinline__ void async16(const u16* g, u16* l) {
    __builtin_amdgcn_global_load_lds(
        (const __attribute__((address_space(1))) u32*)g,
        (__attribute__((address_space(3))) u32*)l, 16, 0, 0);
}

// ---------------------------------------------------------------------------
// prep: x1,x2 fp32->fp16 (row-major), q/k/v fp32->fp16 TRANSPOSED [n][k],
// and cnt zeroing. Same RNE conversions -> downstream math bit-identical.
// ---------------------------------------------------------------------------
__global__ __launch_bounds__(256)
void prep_kernel(const float* __restrict__ x1, const float* __restrict__ x2,
                 const float* __restrict__ qw, const float* __restrict__ kw,
                 const float* __restrict__ vw,
                 u16* __restrict__ x1h, u16* __restrict__ x2h,
                 u16* __restrict__ qT, u16* __restrict__ kT,
                 u16* __restrict__ vT, int* __restrict__ cnt)
{
    const int t = blockIdx.x * 256 + threadIdx.x;
    const int stride = gridDim.x * 256;
    if (t < NPARTS) cnt[t] = 0;

    const int NQ = NN * DD / 4;                 // float4s per x-matrix
    for (int i = t; i < NQ; i += stride) {
        float4 f = ((const float4*)x1)[i];
        ushort4 h;
        h.x = f2h(f.x); h.y = f2h(f.y); h.z = f2h(f.z); h.w = f2h(f.w);
        ((ushort4*)x1h)[i] = h;
        f = ((const float4*)x2)[i];
        h.x = f2h(f.x); h.y = f2h(f.y); h.z = f2h(f.z); h.w = f2h(f.w);
        ((ushort4*)x2h)[i] = h;
    }
    const int NW = DD * DD;                     // per weight matrix
    for (int i = t; i < NW; i += stride) {      // coalesced read, scattered write
        const int k = i >> 9, n = i & 511;
        qT[n * DD + k] = f2h(qw[i]);
        kT[n * DD + k] = f2h(kw[i]);
        vT[n * DD + k] = f2h(vw[i]);
    }
}

// ---------------------------------------------------------------------------
// Projection GEMM v2 (R8/R10 WIN — untouched): pure-async16 staged fp16 GEMM.
// which==2 epilogue packs 4 consecutive-row r-values into one 8B store.
// z=0: Q = x1@q (row-major fp16), z=1: K = x2@k, z=2: VT = (x1@v)^T
// ---------------------------------------------------------------------------
__global__ __launch_bounds__(256, 2)
void proj_kernel(const u16* __restrict__ x1h, const u16* __restrict__ x2h,
                 const u16* __restrict__ qT, const u16* __restrict__ kT,
                 const u16* __restrict__ vT,
                 u16* __restrict__ Qf, u16* __restrict__ Kf, u16* __restrict__ VT)
{
    const int which = blockIdx.z;
    const u16* A = (which == 1) ? x2h : x1h;
    const u16* W = (which == 0) ? qT : (which == 1 ? kT : vT);

    __shared__ u16 Ab[2][128 * 64];   // [m][k], swizzled cols
    __shared__ u16 Wb[2][128 * 64];   // [n][k], swizzled cols

    const int tid  = threadIdx.x;
    const int lane = tid & 63;
    const int wave = tid >> 6;
    const int l15  = lane & 15;
    const int quad = lane >> 4;
    const int wm   = (wave & 1) * 64;
    const int wn   = (wave >> 1) * 64;
    const int m0   = blockIdx.x * 128;
    const int n0   = blockIdx.y * 128;

    const int vrs = lane >> 3;
    const int vch = (lane & 7) ^ vrs;
    int sOff[4];
    for (int i = 0; i < 4; i++) {
        const int c = wave * 4 + i;
        sOff[i] = (c * 8 + vrs) * DD + vch * 8;
    }

    auto stage = [&](int buf, int k0) {
        const u16* a = A + (size_t)m0 * DD + k0;
        const u16* w = W + (size_t)n0 * DD + k0;
        u16* da = &Ab[buf][wave * 2048];
        u16* dw = &Wb[buf][wave * 2048];
        async16(a + sOff[0], da);
        async16(a + sOff[1], da + 512);
        async16(a + sOff[2], da + 1024);
        async16(a + sOff[3], da + 1536);
        async16(w + sOff[0], dw);
        async16(w + sOff[1], dw + 512);
        async16(w + sOff[2], dw + 1024);
        async16(w + sOff[3], dw + 1536);
        __builtin_amdgcn_sched_barrier(0);
    };

    floatx4 acc[4][4] = {};

    stage(0, 0);
    asm volatile("s_waitcnt vmcnt(0)" ::: "memory");
    __syncthreads();

    for (int t = 0; t < 8; t++) {
        if (t < 7) stage((t & 1) ^ 1, (t + 1) * 64);
        const int buf = t & 1;
        __builtin_amdgcn_s_setprio(1);
        for (int ks = 0; ks < 2; ks++) {
            f16x8 af[4], bf[4];
            for (int mi = 0; mi < 4; mi++) {
                const int row = wm + mi * 16 + l15;
                const int ch  = (ks * 4 + quad) ^ (l15 & 7);
                af[mi] = *(const f16x8*)&Ab[buf][row * 64 + ch * 8];
            }
            for (int ni = 0; ni < 4; ni++) {
                const int row = wn + ni * 16 + l15;
                const int ch  = (ks * 4 + quad) ^ (l15 & 7);
                bf[ni] = *(const f16x8*)&Wb[buf][row * 64 + ch * 8];
            }
            for (int mi = 0; mi < 4; mi++)
                for (int ni = 0; ni < 4; ni++)
                    acc[mi][ni] = __builtin_amdgcn_mfma_f32_16x16x32_f16(
                        af[mi], bf[ni], acc[mi][ni], 0, 0, 0);
        }
        __builtin_amdgcn_s_setprio(0);
        asm volatile("s_waitcnt vmcnt(0)" ::: "memory");
        __syncthreads();
    }

    for (int mi = 0; mi < 4; mi++)
        for (int ni = 0; ni < 4; ni++) {
            if (which == 2) {
                // VT[col][row0..row0+3]: 4 consecutive u16 -> one 8B store.
                const int row0 = m0 + wm + mi * 16 + quad * 4;
                const int col  = n0 + wn + ni * 16 + l15;
                uint2 p;
                p.x = ((u32)f2h(acc[mi][ni][1]) << 16) | f2h(acc[mi][ni][0]);
                p.y = ((u32)f2h(acc[mi][ni][3]) << 16) | f2h(acc[mi][ni][2]);
                *(uint2*)&VT[(size_t)col * NN + row0] = p;
            } else {
                for (int r = 0; r < 4; r++) {
                    const int row = m0 + wm + mi * 16 + quad * 4 + r;
                    const int col = n0 + wn + ni * 16 + l15;
                    const u16 hv = f2h(acc[mi][ni][r]);
                    if (which == 0) Qf[(size_t)row * DD + col] = hv;
                    else            Kf[(size_t)row * DD + col] = hv;
                }
            }
        }
}

// ---------------------------------------------------------------------------
// Flash attention partials — 8-WAVE BLOCK, 6-SLOT RING, 4 MERGED GROUPS.
// R11 delta (only): T13 defer-max, THR=5. Skip max-reduce + alpha + O-rescale
// unless some lane's LOCAL tile max exceeds m_run + 5 (exact: reduced max >
// m_run+THR <=> some local max > m_run+THR). Skipped path: P = exp(s-m_old)
// <= e^5 = 148 — safe in fp16 for P, l_run, and the fp16 Opart epilogue
// (THR=8 would risk fp16 overflow in unnormalized O). combine is invariant
// to lagged m_p (w_p = exp(m_p - M) compensates exactly). Branch is
// wave-uniform (__any). alpha[] lives only inside the rare branch.
// Logit scale: QK sigma ~7.5 -> max grows >5 only in first ~2-3 tiles.
// R9 wall (documented): 512-thread blocks cap at 256 regs/wave; this kernel
// sits at exactly 128 VGPR + 128 AGPR. Do not add live state to the loop.
// ---------------------------------------------------------------------------
__global__ __launch_bounds__(512, 2)
void attn_kernel(const u16* __restrict__ Qf, const u16* __restrict__ Kf,
                 const u16* __restrict__ VT,
                 u16* __restrict__ Opart, float* __restrict__ Mp,
                 float* __restrict__ Lp, int* __restrict__ cnt)
{
    const int tid  = threadIdx.x;
    const int lane = tid & 63;
    const int wave = tid >> 6;      // 0..7
    const int w3   = wave & 3;
    const int wsel = wave >> 2;     // 0: stages region A, 1: region B
    const int l15  = lane & 15;
    const int quad = lane >> 4;

    __shared__ u16 KV[6][8192];         // 6 x 16KB ring (96KB)
    __shared__ u16 Ps[8][16 * 68];      // per-wave P transpose
    __shared__ int sPart, sRb;

    // ---- claim work item pinned to this block's physical XCD group ----
    if (tid == 0) {
        u32 xcd;
        asm volatile("s_getreg_b32 %0, hwreg(HW_REG_XCC_ID)" : "=s"(xcd));
        xcd &= 3;                       // 4 queues, XCDs p and p+4 share queue p
        int part = -1, rb = 0;
        for (int t = 0; t < 4; t++) {
            const int p = (xcd + t) & 3;
            const int idx = atomicAdd(&cnt[p], 1);
            if (idx < RB_PER_PART) { part = p; rb = idx; break; }
        }
        sPart = part; sRb = rb;
    }
    __syncthreads();
    const int part = sPart;
    const int rb   = sRb;
    if (part < 0) return;               // unreachable (pigeonhole: 64*4 == 256)

    // 16 Q-rows per wave; 64 blocks/part * 128 rows == 8192 exact
    const int q0 = rb * 128 + wave * 16;

    // Q register-resident (16 A-frags, full D=512)
    f16x8 qf[16];
    for (int kk = 0; kk < 16; kk++)
        qf[kk] = *(const f16x8*)&Qf[(size_t)(q0 + l15) * DD + kk * 32 + quad * 8];

    floatx4 o[32] = {};
    float m_run[4], l_run[4];
    for (int r = 0; r < 4; r++) { m_run[r] = -1e30f; l_run[r] = 0.f; }

    const int j_begin = part * JCHUNK;
    const int j_end   = j_begin + JCHUNK;

    // --- staging offsets, precomputed ONCE (8 persistent ints, static idx).
    const int krow4  = lane >> 4;        // K: row-sub 0..3
    const int kpos16 = lane & 15;        // K: chunk pos in row
    const int vrs    = lane >> 3;        // V: row-sub 0..7
    const int vch    = (lane & 7) ^ vrs; // V: swizzled source chunk

    int kOff[4], vOff[4];
    for (int i = 0; i < 4; i++) {
        const int c    = w3 * 4 + i;
        const int krow = c * 4 + krow4;
        kOff[i] = krow * DD + (kpos16 ^ (krow & 7)) * 8;
        vOff[i] = (c * 8 + vrs) * NN + vch * 8;
    }

    auto stageK = [&](int dq, int j0, int slot) {
        const u16* b = Kf + (size_t)j0 * DD + dq * 128;
        u16* d = &KV[slot][w3 * 2048];
        async16(b + kOff[0], d);
        async16(b + kOff[1], d + 512);
        async16(b + kOff[2], d + 1024);
        async16(b + kOff[3], d + 1536);
        __builtin_amdgcn_sched_barrier(0);
    };
    auto stageV = [&](int dq, int j0, int slot) {
        const u16* b = VT + (size_t)dq * 128 * NN + j0;
        u16* d = &KV[slot][w3 * 2048];
        async16(b + vOff[0], d);
        async16(b + vOff[1], d + 512);
        async16(b + vOff[2], d + 1024);
        async16(b + vOff[3], d + 1536);
        __builtin_amdgcn_sched_barrier(0);
    };

    // --- compute: QK / PV quarters (16 ds_read_b128 + 16 MFMA each) ---
    auto qkQ = [&](int rg, int dq, floatx4* s) {
        __builtin_amdgcn_s_setprio(1);
        for (int k8 = 0; k8 < 4; k8++)
            for (int nt = 0; nt < 4; nt++) {
                const int row = nt * 16 + l15;
                const int ch  = (k8 * 4 + quad) ^ (l15 & 7);
                f16x8 b = *(const f16x8*)&KV[rg][row * 128 + ch * 8];
                s[nt] = __builtin_amdgcn_mfma_f32_16x16x32_f16(qf[dq * 4 + k8], b, s[nt], 0, 0, 0);
            }
        __builtin_amdgcn_s_setprio(0);
    };
    // pf reloaded from Ps inside each PV quarter (short live range — register
    // budget is exactly at the 256/wave cap, R4/R9 lesson)
    auto pvQ = [&](int rg, int dq) {
        f16x8 pf0 = *(const f16x8*)&Ps[wave][l15 * 68 + quad * 8];
        f16x8 pf1 = *(const f16x8*)&Ps[wave][l15 * 68 + 32 + quad * 8];
        __builtin_amdgcn_s_setprio(1);
        for (int t = 0; t < 8; t++) {
            const int row = t * 16 + l15;
            const int c0  = quad ^ (l15 & 7);
            const int c1  = (4 + quad) ^ (l15 & 7);
            f16x8 b0 = *(const f16x8*)&KV[rg][row * 64 + c0 * 8];
            f16x8 b1 = *(const f16x8*)&KV[rg][row * 64 + c1 * 8];
            o[dq * 8 + t] = __builtin_amdgcn_mfma_f32_16x16x32_f16(pf0, b0, o[dq * 8 + t], 0, 0, 0);
            o[dq * 8 + t] = __builtin_amdgcn_mfma_f32_16x16x32_f16(pf1, b1, o[dq * 8 + t], 0, 0, 0);
        }
        __builtin_amdgcn_s_setprio(0);
    };

    // Group barrier: every wave drains all but its newest 4-load group.
    auto pbar = [&]() {
        asm volatile("s_waitcnt vmcnt(4)" ::: "memory");
        asm volatile("s_barrier" ::: "memory");
    };
    auto wrap6 = [](int x) { return x >= 6 ? x - 6 : x; };

    // preamble: K quarters 0..3 of j_begin -> slots 0..3; full drain.
    if (wsel == 0) { stageK(0, j_begin, 0); stageK(2, j_begin, 2); }
    else           { stageK(1, j_begin, 1); stageK(3, j_begin, 3); }
    asm volatile("s_waitcnt vmcnt(0)" ::: "memory");
    asm volatile("s_barrier" ::: "memory");

    int sc = 4;   // next free slot pair

    for (int j0 = j_begin; j0 < j_end; j0 += 64) {
        const int jn = (j0 + 64 < j_end) ? j0 + 64 : j_begin;  // wrap: uniform count
        floatx4 s[4] = {};
        int sA, sB, cA, cB;

        // ---- G0: stage V{0,1}@j0; consume QK quarters 0,1 ----
        sA = sc; sB = sc + 1; cA = wrap6(sc + 2); cB = cA + 1; sc = cA;
        if (wsel == 0) stageV(0, j0, sA); else stageV(1, j0, sB);
        qkQ(cA, 0, s);
        qkQ(cB, 1, s);
        pbar();

        // ---- G1: stage V{2,3}@j0; consume QK quarters 2,3 + softmax + P ----
        sA = sc; sB = sc + 1; cA = wrap6(sc + 2); cB = cA + 1; sc = cA;
        if (wsel == 0) stageV(2, j0, sA); else stageV(3, j0, sB);
        qkQ(cA, 2, s);
        qkQ(cB, 3, s);

        // leaky relu
        for (int nt = 0; nt < 4; nt++)
            for (int r = 0; r < 4; r++) {
                float x = s[nt][r];
                s[nt][r] = x >= 0.f ? x : 0.01f * x;
            }

        // T13 defer-max: local (pre-reduce) tile max per r
        float loc[4];
        for (int r = 0; r < 4; r++)
            loc[r] = fmaxf(fmaxf(s[0][r], s[1][r]), fmaxf(s[2][r], s[3][r]));
        const bool grow = (loc[0] > m_run[0] + 5.f) | (loc[1] > m_run[1] + 5.f) |
                          (loc[2] > m_run[2] + 5.f) | (loc[3] > m_run[3] + 5.f);
        if (__any(grow)) {
            // full path: reduce, update m_run, rescale o and l_run
            float mt4[4];
            for (int r = 0; r < 4; r++) mt4[r] = loc[r];
            for (int off = 1; off < 16; off <<= 1)
                for (int r = 0; r < 4; r++)
                    mt4[r] = fmaxf(mt4[r], __shfl_xor(mt4[r], off));
            float alpha[4];
            for (int r = 0; r < 4; r++) {
                const float mnew = fmaxf(m_run[r], mt4[r]);
                alpha[r] = __expf(m_run[r] - mnew);
                m_run[r] = mnew;
                l_run[r] *= alpha[r];
            }
            for (int i = 0; i < 32; i++)
                for (int r = 0; r < 4; r++)
                    o[i][r] *= alpha[r];
        }

        // common path: P = exp(s - m_run) (bounded by e^5 when deferred)
        float ls[4] = {0.f, 0.f, 0.f, 0.f};
        u16 pv[4][4];
        for (int nt = 0; nt < 4; nt++)
            for (int r = 0; r < 4; r++) {
                const float p = __expf(s[nt][r] - m_run[r]);
                ls[r] += p;
                pv[nt][r] = f2h(p);
            }
        for (int off = 1; off < 16; off <<= 1)
            for (int r = 0; r < 4; r++)
                ls[r] += __shfl_xor(ls[r], off);
        for (int r = 0; r < 4; r++)
            l_run[r] += ls[r];

        // P: C-layout -> A-layout via per-wave LDS (same-wave, lgkm only)
        for (int nt = 0; nt < 4; nt++)
            for (int r = 0; r < 4; r++)
                Ps[wave][(quad * 4 + r) * 68 + nt * 16 + l15] = pv[nt][r];
        asm volatile("s_waitcnt lgkmcnt(0)" ::: "memory");

        pbar();

        // ---- G2: stage K{0,1}@jn; consume PV quarters 0,1 ----
        sA = sc; sB = sc + 1; cA = wrap6(sc + 2); cB = cA + 1; sc = cA;
        if (wsel == 0) stageK(0, jn, sA); else stageK(1, jn, sB);
        pvQ(cA, 0);
        pvQ(cB, 1);
        pbar();

        // ---- G3: stage K{2,3}@jn; consume PV quarters 2,3 ----
        sA = sc; sB = sc + 1; cA = wrap6(sc + 2); cB = cA + 1; sc = cA;
        if (wsel == 0) stageK(2, jn, sA); else stageK(3, jn, sB);
        pvQ(cA, 2);
        pvQ(cB, 3);
        pbar();
    }

    // drain remaining DMA before epilogue / endpgm
    asm volatile("s_waitcnt vmcnt(0)" ::: "memory");

    // ---- epilogue: fp16 un-normalized O + fp32 m,l ----
    for (int i = 0; i < 32; i++)
        for (int r = 0; r < 4; r++) {
            const int row = q0 + quad * 4 + r;
            const int col = i * 16 + l15;
            Opart[((size_t)part * NN + row) * DD + col] = f2h(o[i][r]);
        }
    if (l15 == 0)
        for (int r = 0; r < 4; r++) {
            const int row = q0 + quad * 4 + r;
            Mp[part * NN + row] = m_run[r];
            Lp[part * NN + row] = l_run[r];
        }
}

// ---------------------------------------------------------------------------
// Combine NPARTS j-partials: out = sum_p w_p O_p / sum_p w_p l_p
// Vectorized: 64 threads/row, 8 cols/thread via f16x8 (16B/lane).
// (Math invariant to lagged m_p from defer-max: w_p = exp(m_p - M).)
// ---------------------------------------------------------------------------
__global__ __launch_bounds__(256)
void combine_kernel(const u16* __restrict__ Opart, const float* __restrict__ Mp,
                    const float* __restrict__ Lp, float* __restrict__ out)
{
    const int t   = blockIdx.x * 256 + threadIdx.x;
    const int row = t >> 6;            // 64 threads per row
    const int c0  = (t & 63) * 8;      // 8 cols per thread

    float m[NPARTS], l[NPARTS];
    float M = -1e30f;
    for (int p = 0; p < NPARTS; p++) {
        m[p] = Mp[p * NN + row];
        l[p] = Lp[p * NN + row];
        M = fmaxf(M, m[p]);
    }
    float w[NPARTS], L = 0.f;
    for (int p = 0; p < NPARTS; p++) { w[p] = __expf(m[p] - M); L += w[p] * l[p]; }
    const float inv = 1.f / L;

    float acc[8] = {};
    for (int p = 0; p < NPARTS; p++) {
        f16x8 v = *(const f16x8*)&Opart[((size_t)p * NN + row) * DD + c0];
        for (int j = 0; j < 8; j++)
            acc[j] += w[p] * (float)v[j];
    }
    float4 o0, o1;
    o0.x = acc[0] * inv; o0.y = acc[1] * inv; o0.z = acc[2] * inv; o0.w = acc[3] * inv;
    o1.x = acc[4] * inv; o1.y = acc[5] * inv; o1.z = acc[6] * inv; o1.w = acc[7] * inv;
    *(float4*)&out[(size_t)row * DD + c0]     = o0;
    *(float4*)&out[(size_t)row * DD + c0 + 4] = o1;
}

// ---------------------------------------------------------------------------
extern "C" void kernel_launch(void* const* d_in, const int* in_sizes, int n_in,
                              void* d_out, int out_size, void* d_ws, size_t ws_size,
                              hipStream_t stream)
{
    const float* x1 = (const float*)d_in[0];
    const float* x2 = (const float*)d_in[1];
    const float* qw = (const float*)d_in[2];
    const float* kw = (const float*)d_in[3];
    const float* vw = (const float*)d_in[4];
    float* out = (float*)d_out;

    // workspace: Qf|Kf|VT (8MB each fp16) | Opart 32MB fp16 | Mp | Lp | cnt
    //            | x1h | x2h (8MB each fp16) | qT|kT|vT (0.5MB each fp16)
    u16* Qf = (u16*)d_ws;
    u16* Kf = Qf + (size_t)NN * DD;
    u16* VT = Kf + (size_t)NN * DD;
    u16* Opart = VT + (size_t)NN * DD;
    float* Mp = (float*)(Opart + (size_t)NPARTS * NN * DD);
    float* Lp = Mp + NPARTS * NN;
    int* cnt = (int*)(Lp + NPARTS * NN);
    u16* x1h = (u16*)(cnt + 8);        // 16B-aligned
    u16* x2h = x1h + (size_t)NN * DD;
    u16* qT  = x2h + (size_t)NN * DD;
    u16* kT  = qT + DD * DD;
    u16* vT  = kT + DD * DD;

    prep_kernel<<<1024, 256, 0, stream>>>(x1, x2, qw, kw, vw,
                                          x1h, x2h, qT, kT, vT, cnt);
    proj_kernel<<<dim3(64, 4, 3), 256, 0, stream>>>(x1h, x2h, qT, kT, vT,
                                                    Qf, Kf, VT);
    attn_kernel<<<dim3(RB_PER_PART * NPARTS), 512, 0, stream>>>(Qf, Kf, VT, Opart, Mp, Lp, cnt);
    combine_kernel<<<(NN * 64) / 256, 256, 0, stream>>>(Opart, Mp, Lp, out);
}

// Round 12
// 351.541 us; speedup vs baseline: 2.0804x; 2.0804x over previous
//
#include <hip/hip_runtime.h>
#include <hip/hip_bf16.h>

typedef unsigned short u16;
typedef unsigned int u32;
typedef float floatx4 __attribute__((ext_vector_type(4)));
typedef _Float16 f16x8 __attribute__((ext_vector_type(8)));

#define NN 8192
#define DD 512
#define NPARTS 4
#define JCHUNK 2048       // NN / NPARTS
#define RB_PER_PART 64    // 128-row blocks: 64*128 == 8192 exactly

__device__ __forceinline__ u16 f2h(float f) {
    _Float16 h = (_Float16)f;                 // RNE
    return __builtin_bit_cast(u16, h);
}
__device__ __forceinline__ float h2f(u16 u) {
    _Float16 h = __builtin_bit_cast(_Float16, u);
    return (float)h;
}

// async 16B-per-lane global->LDS DMA (wave-uniform LDS base + lane*16).
__device__ __forceinline__ void async16(const u16* g, u16* l) {
    __builtin_amdgcn_global_load_lds(
        (const __attribute__((address_space(1))) u32*)g,
        (__attribute__((address_space(3))) u32*)l, 16, 0, 0);
}

// ---------------------------------------------------------------------------
// prep: x1,x2 fp32->fp16 (row-major), q/k/v fp32->fp16 TRANSPOSED [n][k],
// and cnt zeroing. Same RNE conversions -> downstream math bit-identical.
// ---------------------------------------------------------------------------
__global__ __launch_bounds__(256)
void prep_kernel(const float* __restrict__ x1, const float* __restrict__ x2,
                 const float* __restrict__ qw, const float* __restrict__ kw,
                 const float* __restrict__ vw,
                 u16* __restrict__ x1h, u16* __restrict__ x2h,
                 u16* __restrict__ qT, u16* __restrict__ kT,
                 u16* __restrict__ vT, int* __restrict__ cnt)
{
    const int t = blockIdx.x * 256 + threadIdx.x;
    const int stride = gridDim.x * 256;
    if (t < NPARTS) cnt[t] = 0;

    const int NQ = NN * DD / 4;                 // float4s per x-matrix
    for (int i = t; i < NQ; i += stride) {
        float4 f = ((const float4*)x1)[i];
        ushort4 h;
        h.x = f2h(f.x); h.y = f2h(f.y); h.z = f2h(f.z); h.w = f2h(f.w);
        ((ushort4*)x1h)[i] = h;
        f = ((const float4*)x2)[i];
        h.x = f2h(f.x); h.y = f2h(f.y); h.z = f2h(f.z); h.w = f2h(f.w);
        ((ushort4*)x2h)[i] = h;
    }
    const int NW = DD * DD;                     // per weight matrix
    for (int i = t; i < NW; i += stride) {      // coalesced read, scattered write
        const int k = i >> 9, n = i & 511;
        qT[n * DD + k] = f2h(qw[i]);
        kT[n * DD + k] = f2h(kw[i]);
        vT[n * DD + k] = f2h(vw[i]);
    }
}

// ---------------------------------------------------------------------------
// Projection GEMM v2 (R8/R10 WIN): pure-async16 staged fp16 GEMM.
// which==2 epilogue packs 4 consecutive-row r-values into one 8B store.
// z=0: Q = x1@q (row-major fp16), z=1: K = x2@k, z=2: VT = (x1@v)^T
// ---------------------------------------------------------------------------
__global__ __launch_bounds__(256, 2)
void proj_kernel(const u16* __restrict__ x1h, const u16* __restrict__ x2h,
                 const u16* __restrict__ qT, const u16* __restrict__ kT,
                 const u16* __restrict__ vT,
                 u16* __restrict__ Qf, u16* __restrict__ Kf, u16* __restrict__ VT)
{
    const int which = blockIdx.z;
    const u16* A = (which == 1) ? x2h : x1h;
    const u16* W = (which == 0) ? qT : (which == 1 ? kT : vT);

    __shared__ u16 Ab[2][128 * 64];   // [m][k], swizzled cols
    __shared__ u16 Wb[2][128 * 64];   // [n][k], swizzled cols

    const int tid  = threadIdx.x;
    const int lane = tid & 63;
    const int wave = tid >> 6;
    const int l15  = lane & 15;
    const int quad = lane >> 4;
    const int wm   = (wave & 1) * 64;
    const int wn   = (wave >> 1) * 64;
    const int m0   = blockIdx.x * 128;
    const int n0   = blockIdx.y * 128;

    const int vrs = lane >> 3;
    const int vch = (lane & 7) ^ vrs;
    int sOff[4];
    for (int i = 0; i < 4; i++) {
        const int c = wave * 4 + i;
        sOff[i] = (c * 8 + vrs) * DD + vch * 8;
    }

    auto stage = [&](int buf, int k0) {
        const u16* a = A + (size_t)m0 * DD + k0;
        const u16* w = W + (size_t)n0 * DD + k0;
        u16* da = &Ab[buf][wave * 2048];
        u16* dw = &Wb[buf][wave * 2048];
        async16(a + sOff[0], da);
        async16(a + sOff[1], da + 512);
        async16(a + sOff[2], da + 1024);
        async16(a + sOff[3], da + 1536);
        async16(w + sOff[0], dw);
        async16(w + sOff[1], dw + 512);
        async16(w + sOff[2], dw + 1024);
        async16(w + sOff[3], dw + 1536);
        __builtin_amdgcn_sched_barrier(0);
    };

    floatx4 acc[4][4] = {};

    stage(0, 0);
    asm volatile("s_waitcnt vmcnt(0)" ::: "memory");
    __syncthreads();

    for (int t = 0; t < 8; t++) {
        if (t < 7) stage((t & 1) ^ 1, (t + 1) * 64);
        const int buf = t & 1;
        __builtin_amdgcn_s_setprio(1);
        for (int ks = 0; ks < 2; ks++) {
            f16x8 af[4], bf[4];
            for (int mi = 0; mi < 4; mi++) {
                const int row = wm + mi * 16 + l15;
                const int ch  = (ks * 4 + quad) ^ (l15 & 7);
                af[mi] = *(const f16x8*)&Ab[buf][row * 64 + ch * 8];
            }
            for (int ni = 0; ni < 4; ni++) {
                const int row = wn + ni * 16 + l15;
                const int ch  = (ks * 4 + quad) ^ (l15 & 7);
                bf[ni] = *(const f16x8*)&Wb[buf][row * 64 + ch * 8];
            }
            for (int mi = 0; mi < 4; mi++)
                for (int ni = 0; ni < 4; ni++)
                    acc[mi][ni] = __builtin_amdgcn_mfma_f32_16x16x32_f16(
                        af[mi], bf[ni], acc[mi][ni], 0, 0, 0);
        }
        __builtin_amdgcn_s_setprio(0);
        asm volatile("s_waitcnt vmcnt(0)" ::: "memory");
        __syncthreads();
    }

    for (int mi = 0; mi < 4; mi++)
        for (int ni = 0; ni < 4; ni++) {
            if (which == 2) {
                // VT[col][row0..row0+3]: 4 consecutive u16 -> one 8B store.
                const int row0 = m0 + wm + mi * 16 + quad * 4;
                const int col  = n0 + wn + ni * 16 + l15;
                uint2 p;
                p.x = ((u32)f2h(acc[mi][ni][1]) << 16) | f2h(acc[mi][ni][0]);
                p.y = ((u32)f2h(acc[mi][ni][3]) << 16) | f2h(acc[mi][ni][2]);
                *(uint2*)&VT[(size_t)col * NN + row0] = p;
            } else {
                for (int r = 0; r < 4; r++) {
                    const int row = m0 + wm + mi * 16 + quad * 4 + r;
                    const int col = n0 + wn + ni * 16 + l15;
                    const u16 hv = f2h(acc[mi][ni][r]);
                    if (which == 0) Qf[(size_t)row * DD + col] = hv;
                    else            Kf[(size_t)row * DD + col] = hv;
                }
            }
        }
}

// ---------------------------------------------------------------------------
// Flash attention partials — 8-WAVE BLOCK, 6-SLOT RING, 4 MERGED GROUPS.
// (R7/R8/R10 WIN structure — byte-exact revert of R11.)
// ZERO-HEADROOM WALL (proven 3x: R1, R9, R11): this kernel sits at exactly
// 128 VGPR + 128 AGPR = the 256-regs/wave HW cap for 512-thread blocks.
// R11: even T13 defer-max (~8 extra live scalars + a control-flow join)
// spilled qf[16] -> 2.1 GB phantom HBM traffic, attn 262->638 µs. Do NOT
// add live state or control-flow joins to the main loop. The existing
// __any(need) rescale-skip is the register-free form of defer-max.
// ---------------------------------------------------------------------------
__global__ __launch_bounds__(512, 2)
void attn_kernel(const u16* __restrict__ Qf, const u16* __restrict__ Kf,
                 const u16* __restrict__ VT,
                 u16* __restrict__ Opart, float* __restrict__ Mp,
                 float* __restrict__ Lp, int* __restrict__ cnt)
{
    const int tid  = threadIdx.x;
    const int lane = tid & 63;
    const int wave = tid >> 6;      // 0..7
    const int w3   = wave & 3;
    const int wsel = wave >> 2;     // 0: stages region A, 1: region B
    const int l15  = lane & 15;
    const int quad = lane >> 4;

    __shared__ u16 KV[6][8192];         // 6 x 16KB ring (96KB)
    __shared__ u16 Ps[8][16 * 68];      // per-wave P transpose
    __shared__ int sPart, sRb;

    // ---- claim work item pinned to this block's physical XCD group ----
    if (tid == 0) {
        u32 xcd;
        asm volatile("s_getreg_b32 %0, hwreg(HW_REG_XCC_ID)" : "=s"(xcd));
        xcd &= 3;                       // 4 queues, XCDs p and p+4 share queue p
        int part = -1, rb = 0;
        for (int t = 0; t < 4; t++) {
            const int p = (xcd + t) & 3;
            const int idx = atomicAdd(&cnt[p], 1);
            if (idx < RB_PER_PART) { part = p; rb = idx; break; }
        }
        sPart = part; sRb = rb;
    }
    __syncthreads();
    const int part = sPart;
    const int rb   = sRb;
    if (part < 0) return;               // unreachable (pigeonhole: 64*4 == 256)

    // 16 Q-rows per wave; 64 blocks/part * 128 rows == 8192 exact
    const int q0 = rb * 128 + wave * 16;

    // Q register-resident (16 A-frags, full D=512)
    f16x8 qf[16];
    for (int kk = 0; kk < 16; kk++)
        qf[kk] = *(const f16x8*)&Qf[(size_t)(q0 + l15) * DD + kk * 32 + quad * 8];

    floatx4 o[32] = {};
    float m_run[4], l_run[4];
    for (int r = 0; r < 4; r++) { m_run[r] = -1e30f; l_run[r] = 0.f; }

    const int j_begin = part * JCHUNK;
    const int j_end   = j_begin + JCHUNK;

    // --- staging offsets, precomputed ONCE (8 persistent ints, static idx).
    const int krow4  = lane >> 4;        // K: row-sub 0..3
    const int kpos16 = lane & 15;        // K: chunk pos in row
    const int vrs    = lane >> 3;        // V: row-sub 0..7
    const int vch    = (lane & 7) ^ vrs; // V: swizzled source chunk

    int kOff[4], vOff[4];
    for (int i = 0; i < 4; i++) {
        const int c    = w3 * 4 + i;
        const int krow = c * 4 + krow4;
        kOff[i] = krow * DD + (kpos16 ^ (krow & 7)) * 8;
        vOff[i] = (c * 8 + vrs) * NN + vch * 8;
    }

    auto stageK = [&](int dq, int j0, int slot) {
        const u16* b = Kf + (size_t)j0 * DD + dq * 128;
        u16* d = &KV[slot][w3 * 2048];
        async16(b + kOff[0], d);
        async16(b + kOff[1], d + 512);
        async16(b + kOff[2], d + 1024);
        async16(b + kOff[3], d + 1536);
        __builtin_amdgcn_sched_barrier(0);
    };
    auto stageV = [&](int dq, int j0, int slot) {
        const u16* b = VT + (size_t)dq * 128 * NN + j0;
        u16* d = &KV[slot][w3 * 2048];
        async16(b + vOff[0], d);
        async16(b + vOff[1], d + 512);
        async16(b + vOff[2], d + 1024);
        async16(b + vOff[3], d + 1536);
        __builtin_amdgcn_sched_barrier(0);
    };

    // --- compute: QK / PV quarters (16 ds_read_b128 + 16 MFMA each) ---
    auto qkQ = [&](int rg, int dq, floatx4* s) {
        __builtin_amdgcn_s_setprio(1);
        for (int k8 = 0; k8 < 4; k8++)
            for (int nt = 0; nt < 4; nt++) {
                const int row = nt * 16 + l15;
                const int ch  = (k8 * 4 + quad) ^ (l15 & 7);
                f16x8 b = *(const f16x8*)&KV[rg][row * 128 + ch * 8];
                s[nt] = __builtin_amdgcn_mfma_f32_16x16x32_f16(qf[dq * 4 + k8], b, s[nt], 0, 0, 0);
            }
        __builtin_amdgcn_s_setprio(0);
    };
    // pf reloaded from Ps inside each PV quarter (short live range — register
    // budget is exactly at the 256/wave cap, R4/R9 lesson)
    auto pvQ = [&](int rg, int dq) {
        f16x8 pf0 = *(const f16x8*)&Ps[wave][l15 * 68 + quad * 8];
        f16x8 pf1 = *(const f16x8*)&Ps[wave][l15 * 68 + 32 + quad * 8];
        __builtin_amdgcn_s_setprio(1);
        for (int t = 0; t < 8; t++) {
            const int row = t * 16 + l15;
            const int c0  = quad ^ (l15 & 7);
            const int c1  = (4 + quad) ^ (l15 & 7);
            f16x8 b0 = *(const f16x8*)&KV[rg][row * 64 + c0 * 8];
            f16x8 b1 = *(const f16x8*)&KV[rg][row * 64 + c1 * 8];
            o[dq * 8 + t] = __builtin_amdgcn_mfma_f32_16x16x32_f16(pf0, b0, o[dq * 8 + t], 0, 0, 0);
            o[dq * 8 + t] = __builtin_amdgcn_mfma_f32_16x16x32_f16(pf1, b1, o[dq * 8 + t], 0, 0, 0);
        }
        __builtin_amdgcn_s_setprio(0);
    };

    // Group barrier: every wave drains all but its newest 4-load group.
    auto pbar = [&]() {
        asm volatile("s_waitcnt vmcnt(4)" ::: "memory");
        asm volatile("s_barrier" ::: "memory");
    };
    auto wrap6 = [](int x) { return x >= 6 ? x - 6 : x; };

    // preamble: K quarters 0..3 of j_begin -> slots 0..3; full drain.
    if (wsel == 0) { stageK(0, j_begin, 0); stageK(2, j_begin, 2); }
    else           { stageK(1, j_begin, 1); stageK(3, j_begin, 3); }
    asm volatile("s_waitcnt vmcnt(0)" ::: "memory");
    asm volatile("s_barrier" ::: "memory");

    int sc = 4;   // next free slot pair

    for (int j0 = j_begin; j0 < j_end; j0 += 64) {
        const int jn = (j0 + 64 < j_end) ? j0 + 64 : j_begin;  // wrap: uniform count
        floatx4 s[4] = {};
        int sA, sB, cA, cB;

        // ---- G0: stage V{0,1}@j0; consume QK quarters 0,1 ----
        sA = sc; sB = sc + 1; cA = wrap6(sc + 2); cB = cA + 1; sc = cA;
        if (wsel == 0) stageV(0, j0, sA); else stageV(1, j0, sB);
        qkQ(cA, 0, s);
        qkQ(cB, 1, s);
        pbar();

        // ---- G1: stage V{2,3}@j0; consume QK quarters 2,3 + softmax + P ----
        sA = sc; sB = sc + 1; cA = wrap6(sc + 2); cB = cA + 1; sc = cA;
        if (wsel == 0) stageV(2, j0, sA); else stageV(3, j0, sB);
        qkQ(cA, 2, s);
        qkQ(cB, 3, s);

        for (int nt = 0; nt < 4; nt++)
            for (int r = 0; r < 4; r++) {
                float x = s[nt][r];
                s[nt][r] = x >= 0.f ? x : 0.01f * x;
            }
        float mt4[4];
        for (int r = 0; r < 4; r++)
            mt4[r] = fmaxf(fmaxf(s[0][r], s[1][r]), fmaxf(s[2][r], s[3][r]));
        for (int off = 1; off < 16; off <<= 1)
            for (int r = 0; r < 4; r++)
                mt4[r] = fmaxf(mt4[r], __shfl_xor(mt4[r], off));

        float alpha[4];
        for (int r = 0; r < 4; r++) {
            const float mnew = fmaxf(m_run[r], mt4[r]);
            alpha[r] = __expf(m_run[r] - mnew);
            m_run[r] = mnew;
        }
        float ls[4] = {0.f, 0.f, 0.f, 0.f};
        u16 pv[4][4];
        for (int nt = 0; nt < 4; nt++)
            for (int r = 0; r < 4; r++) {
                const float p = __expf(s[nt][r] - m_run[r]);
                ls[r] += p;
                pv[nt][r] = f2h(p);
            }
        for (int off = 1; off < 16; off <<= 1)
            for (int r = 0; r < 4; r++)
                ls[r] += __shfl_xor(ls[r], off);
        for (int r = 0; r < 4; r++)
            l_run[r] = l_run[r] * alpha[r] + ls[r];
        const bool need = (alpha[0] != 1.f) | (alpha[1] != 1.f) |
                          (alpha[2] != 1.f) | (alpha[3] != 1.f);
        if (__any(need))
            for (int i = 0; i < 32; i++)
                for (int r = 0; r < 4; r++)
                    o[i][r] *= alpha[r];

        // P: C-layout -> A-layout via per-wave LDS (same-wave, lgkm only)
        for (int nt = 0; nt < 4; nt++)
            for (int r = 0; r < 4; r++)
                Ps[wave][(quad * 4 + r) * 68 + nt * 16 + l15] = pv[nt][r];
        asm volatile("s_waitcnt lgkmcnt(0)" ::: "memory");

        pbar();

        // ---- G2: stage K{0,1}@jn; consume PV quarters 0,1 ----
        sA = sc; sB = sc + 1; cA = wrap6(sc + 2); cB = cA + 1; sc = cA;
        if (wsel == 0) stageK(0, jn, sA); else stageK(1, jn, sB);
        pvQ(cA, 0);
        pvQ(cB, 1);
        pbar();

        // ---- G3: stage K{2,3}@jn; consume PV quarters 2,3 ----
        sA = sc; sB = sc + 1; cA = wrap6(sc + 2); cB = cA + 1; sc = cA;
        if (wsel == 0) stageK(2, jn, sA); else stageK(3, jn, sB);
        pvQ(cA, 2);
        pvQ(cB, 3);
        pbar();
    }

    // drain remaining DMA before epilogue / endpgm
    asm volatile("s_waitcnt vmcnt(0)" ::: "memory");

    // ---- epilogue: fp16 un-normalized O + fp32 m,l ----
    for (int i = 0; i < 32; i++)
        for (int r = 0; r < 4; r++) {
            const int row = q0 + quad * 4 + r;
            const int col = i * 16 + l15;
            Opart[((size_t)part * NN + row) * DD + col] = f2h(o[i][r]);
        }
    if (l15 == 0)
        for (int r = 0; r < 4; r++) {
            const int row = q0 + quad * 4 + r;
            Mp[part * NN + row] = m_run[r];
            Lp[part * NN + row] = l_run[r];
        }
}

// ---------------------------------------------------------------------------
// Combine NPARTS j-partials: out = sum_p w_p O_p / sum_p w_p l_p
// Vectorized: 64 threads/row, 8 cols/thread via f16x8 (16B/lane).
// ---------------------------------------------------------------------------
__global__ __launch_bounds__(256)
void combine_kernel(const u16* __restrict__ Opart, const float* __restrict__ Mp,
                    const float* __restrict__ Lp, float* __restrict__ out)
{
    const int t   = blockIdx.x * 256 + threadIdx.x;
    const int row = t >> 6;            // 64 threads per row
    const int c0  = (t & 63) * 8;      // 8 cols per thread

    float m[NPARTS], l[NPARTS];
    float M = -1e30f;
    for (int p = 0; p < NPARTS; p++) {
        m[p] = Mp[p * NN + row];
        l[p] = Lp[p * NN + row];
        M = fmaxf(M, m[p]);
    }
    float w[NPARTS], L = 0.f;
    for (int p = 0; p < NPARTS; p++) { w[p] = __expf(m[p] - M); L += w[p] * l[p]; }
    const float inv = 1.f / L;

    float acc[8] = {};
    for (int p = 0; p < NPARTS; p++) {
        f16x8 v = *(const f16x8*)&Opart[((size_t)p * NN + row) * DD + c0];
        for (int j = 0; j < 8; j++)
            acc[j] += w[p] * (float)v[j];
    }
    float4 o0, o1;
    o0.x = acc[0] * inv; o0.y = acc[1] * inv; o0.z = acc[2] * inv; o0.w = acc[3] * inv;
    o1.x = acc[4] * inv; o1.y = acc[5] * inv; o1.z = acc[6] * inv; o1.w = acc[7] * inv;
    *(float4*)&out[(size_t)row * DD + c0]     = o0;
    *(float4*)&out[(size_t)row * DD + c0 + 4] = o1;
}

// ---------------------------------------------------------------------------
extern "C" void kernel_launch(void* const* d_in, const int* in_sizes, int n_in,
                              void* d_out, int out_size, void* d_ws, size_t ws_size,
                              hipStream_t stream)
{
    const float* x1 = (const float*)d_in[0];
    const float* x2 = (const float*)d_in[1];
    const float* qw = (const float*)d_in[2];
    const float* kw = (const float*)d_in[3];
    const float* vw = (const float*)d_in[4];
    float* out = (float*)d_out;

    // workspace: Qf|Kf|VT (8MB each fp16) | Opart 32MB fp16 | Mp | Lp | cnt
    //            | x1h | x2h (8MB each fp16) | qT|kT|vT (0.5MB each fp16)
    u16* Qf = (u16*)d_ws;
    u16* Kf = Qf + (size_t)NN * DD;
    u16* VT = Kf + (size_t)NN * DD;
    u16* Opart = VT + (size_t)NN * DD;
    float* Mp = (float*)(Opart + (size_t)NPARTS * NN * DD);
    float* Lp = Mp + NPARTS * NN;
    int* cnt = (int*)(Lp + NPARTS * NN);
    u16* x1h = (u16*)(cnt + 8);        // 16B-aligned
    u16* x2h = x1h + (size_t)NN * DD;
    u16* qT  = x2h + (size_t)NN * DD;
    u16* kT  = qT + DD * DD;
    u16* vT  = kT + DD * DD;

    prep_kernel<<<1024, 256, 0, stream>>>(x1, x2, qw, kw, vw,
                                          x1h, x2h, qT, kT, vT, cnt);
    proj_kernel<<<dim3(64, 4, 3), 256, 0, stream>>>(x1h, x2h, qT, kT, vT,
                                                    Qf, Kf, VT);
    attn_kernel<<<dim3(RB_PER_PART * NPARTS), 512, 0, stream>>>(Qf, Kf, VT, Opart, Mp, Lp, cnt);
    combine_kernel<<<(NN * 64) / 256, 256, 0, stream>>>(Opart, Mp, Lp, out);
}